// Round 6
// baseline (131.566 us; speedup 1.0000x reference)
//
#include <hip/hip_runtime.h>
#include <hip/hip_fp16.h>

// Problem constants (from reference)
constexpr int BATCH    = 4096;
constexpr int IN_DIM   = 1024;
constexpr int HIDDEN   = 8192;
constexpr int N_LAYERS = 6;
constexpr int OUT_DIM  = 8;
constexpr float INV_TAU = 0.1f;

// Tiling
constexpr int TB   = 4;             // batch rows per workgroup
constexpr int NTH  = 1024;          // threads per block (16 waves)
constexpr int NPT  = HIDDEN / NTH;  // neurons per thread = 8 (strided by 1024)
constexpr int NWAVES = NTH / 64;    // 16

__device__ __forceinline__ __half2 u2h(unsigned int u) {
    union { unsigned int u; __half2 h; } v; v.u = u; return v.h;
}
__device__ __forceinline__ unsigned int h2u(__half2 h) {
    union { unsigned int u; __half2 h; } v; v.h = h; return v.u;
}

// pack 4 fp32 -> 4 fp16 in a uint2
__device__ __forceinline__ uint2 pack4(float4 v) {
    __half2 lo = __float22half2_rn(make_float2(v.x, v.y));
    __half2 hi = __float22half2_rn(make_float2(v.z, v.w));
    uint2 r; r.x = h2u(lo); r.y = h2u(hi); return r;
}

// ---------------------------------------------------------------------------
// Kernel 1: packed per-neuron records:
//   coefp[l*H+j] = 4 fp16 gate coefs (c0,c1 | c2,c3)
//   idxp [l*H+j] = ia | (ib << 16)
// ---------------------------------------------------------------------------
__global__ void prep_kernel(const float* __restrict__ logic_w,
                            const int* __restrict__ idx0_a,
                            const int* __restrict__ idx0_b,
                            const int* __restrict__ idx_a,
                            const int* __restrict__ idx_b,
                            uint2* __restrict__ coefp,
                            unsigned int* __restrict__ idxp, int n)
{
    int id = blockIdx.x * blockDim.x + threadIdx.x;
    if (id >= n) return;
    const int l = id / HIDDEN;
    const int j = id - l * HIDDEN;

    int ia, ib;
    if (l == 0) { ia = idx0_a[j]; ib = idx0_b[j]; }
    else        { ia = idx_a[(size_t)(l - 1) * HIDDEN + j];
                  ib = idx_b[(size_t)(l - 1) * HIDDEN + j]; }
    idxp[id] = (unsigned int)ia | ((unsigned int)ib << 16);

    const float4* w4 = (const float4*)(logic_w + (size_t)id * 16);
    float4 wa = w4[0], wb = w4[1], wc = w4[2], wd = w4[3];
    float wv[16] = {wa.x, wa.y, wa.z, wa.w, wb.x, wb.y, wb.z, wb.w,
                    wc.x, wc.y, wc.z, wc.w, wd.x, wd.y, wd.z, wd.w};
    float m = wv[0];
#pragma unroll
    for (int i = 1; i < 16; ++i) m = fmaxf(m, wv[i]);
    float e[16];
    float s = 0.f;
#pragma unroll
    for (int i = 0; i < 16; ++i) { e[i] = expf(wv[i] - m); s += e[i]; }
    float inv = 1.f / s;
    const float G0[16] = {0,0,0,0,0,0,0,0, 1,1,1,1,1,1,1,1};
    const float G1[16] = {0,0,1,1,0,0,1,1, -1,-1,0,0,-1,-1,0,0};
    const float G2[16] = {0,0,0,0,1,1,1,1, -1,-1,-1,-1,0,0,0,0};
    const float G3[16] = {0,1,-1,0,-1,0,-2,-1, 1,2,0,1,0,1,-1,0};
    float c0 = 0.f, c1 = 0.f, c2 = 0.f, c3 = 0.f;
#pragma unroll
    for (int i = 0; i < 16; ++i) {
        float p = e[i] * inv;
        c0 = fmaf(p, G0[i], c0);
        c1 = fmaf(p, G1[i], c1);
        c2 = fmaf(p, G2[i], c2);
        c3 = fmaf(p, G3[i], c3);
    }
    coefp[id] = pack4(make_float4(c0, c1, c2, c3));
}

// gate in packed fp16: r = (c0 + c1*a) + b*(c2 + c3*a), both half2 halves.
__device__ __forceinline__ uint2 gateh(uint2 a, uint2 b, uint2 c) {
    __half2 cp01 = u2h(c.x), cp23 = u2h(c.y);
    __half2 c0 = __low2half2(cp01), c1 = __high2half2(cp01);
    __half2 c2 = __low2half2(cp23), c3 = __high2half2(cp23);
    __half2 alo = u2h(a.x), ahi = u2h(a.y);
    __half2 blo = u2h(b.x), bhi = u2h(b.y);
    __half2 rlo = __hfma2(blo, __hfma2(c3, alo, c2), __hfma2(c1, alo, c0));
    __half2 rhi = __hfma2(bhi, __hfma2(c3, ahi, c2), __hfma2(c1, ahi, c0));
    uint2 r; r.x = h2u(rlo); r.y = h2u(rhi); return r;
}

// ---------------------------------------------------------------------------
// Kernel 2: fused network. TB=4 rows/block. h SPLIT into two b32 arrays
// (hA = rows 0,1 as half2; hB = rows 2,3): random gathers are ds_read_b32
// (1 bank/lane; 2-way aliasing free) instead of b64 (2 banks/lane, heavy
// conflicts). Next-layer indices register-prefetched at the TOP of each
// compute phase so post-barrier critical path starts with gathers.
// ---------------------------------------------------------------------------
__global__ __launch_bounds__(NTH) void net_kernel(
    const float*  __restrict__ x,
    const uint2*  __restrict__ coefp,
    const unsigned int* __restrict__ idxp,
    const float*  __restrict__ scaler_w, const float* __restrict__ scaler_b,
    float* __restrict__ out)
{
    __shared__ unsigned int hA[HIDDEN];     // 32 KB: rows 0,1 (half2)
    __shared__ unsigned int hB[HIDDEN];     // 32 KB: rows 2,3 (half2)
    __shared__ unsigned int hxA[IN_DIM];    // 4 KB
    __shared__ unsigned int hxB[IN_DIM];    // 4 KB
    __shared__ float4 warr[NWAVES];         // 256 B
    __shared__ float  vals[TB][OUT_DIM];    // 128 B

    const int tid = threadIdx.x;
    const int b0  = blockIdx.x * TB;

    // Load + binarize input tile (NTH == IN_DIM)
    {
        float x0 = x[(size_t)(b0 + 0) * IN_DIM + tid];
        float x1 = x[(size_t)(b0 + 1) * IN_DIM + tid];
        float x2 = x[(size_t)(b0 + 2) * IN_DIM + tid];
        float x3 = x[(size_t)(b0 + 3) * IN_DIM + tid];
        __half2 lo = __floats2half2_rn(x0 > 0.5f ? 1.f : 0.f, x1 > 0.5f ? 1.f : 0.f);
        __half2 hi = __floats2half2_rn(x2 > 0.5f ? 1.f : 0.f, x3 > 0.5f ? 1.f : 0.f);
        hxA[tid] = h2u(lo);
        hxB[tid] = h2u(hi);
    }

    uint2 acc[NPT];                // fp16-packed results (16 VGPRs)
    unsigned int ij[NPT];          // current layer's packed indices
    unsigned int ijn[NPT];         // next layer's packed indices (prefetch)

    // Layer 0 indices up-front
#pragma unroll
    for (int k = 0; k < NPT; ++k) ij[k] = idxp[k * NTH + tid];

    __syncthreads();               // hx visible

    // Layer 0: prefetch layer-1 idx, then gather from hx (coef JIT).
#pragma unroll
    for (int k = 0; k < NPT; ++k) ijn[k] = idxp[HIDDEN + k * NTH + tid];
#pragma unroll
    for (int k = 0; k < NPT; ++k) {
        unsigned int pr = ij[k];
        unsigned int ia = pr & 0xffffu, ib = pr >> 16;
        uint2 a = make_uint2(hxA[ia], hxB[ia]);
        uint2 b = make_uint2(hxA[ib], hxB[ib]);
        acc[k] = gateh(a, b, coefp[k * NTH + tid]);
    }
    // hx -> h are disjoint arrays: no barrier needed before these writes
#pragma unroll
    for (int k = 0; k < NPT; ++k) { hA[k * NTH + tid] = acc[k].x; hB[k * NTH + tid] = acc[k].y; }
    __syncthreads();

    // Layers 1..5: in-place on hA/hB (reads land in regs before writes)
#pragma unroll
    for (int l = 1; l < N_LAYERS; ++l) {
#pragma unroll
        for (int k = 0; k < NPT; ++k) ij[k] = ijn[k];
        if (l < N_LAYERS - 1) {
#pragma unroll
            for (int k = 0; k < NPT; ++k)
                ijn[k] = idxp[(size_t)(l + 1) * HIDDEN + k * NTH + tid];
        }
        const uint2* cp = coefp + (size_t)l * HIDDEN;
#pragma unroll
        for (int k = 0; k < NPT; ++k) {
            unsigned int pr = ij[k];
            unsigned int ia = pr & 0xffffu, ib = pr >> 16;
            uint2 a = make_uint2(hA[ia], hB[ia]);
            uint2 b = make_uint2(hA[ib], hB[ib]);
            acc[k] = gateh(a, b, cp[k * NTH + tid]);
        }
        __syncthreads();                    // all reads of h done
#pragma unroll
        for (int k = 0; k < NPT; ++k) { hA[k * NTH + tid] = acc[k].x; hB[k * NTH + tid] = acc[k].y; }
        __syncthreads();
    }

    // Epilogue: group k = tid>>7; sum 8 neurons at stride 128 (conflict-free),
    // fp32 accumulation; 64-lane butterfly; wave wv covers half of group wv>>1.
    {
        const int k    = tid >> 7;
        const int base = k * 1024 + (tid & 127);
        float4 v = make_float4(0.f, 0.f, 0.f, 0.f);
#pragma unroll
        for (int i = 0; i < 8; ++i) {
            float2 lo = __half22float2(u2h(hA[base + 128 * i]));
            float2 hi = __half22float2(u2h(hB[base + 128 * i]));
            v.x += lo.x; v.y += lo.y; v.z += hi.x; v.w += hi.y;
        }
#pragma unroll
        for (int off = 32; off > 0; off >>= 1) {
            v.x += __shfl_down(v.x, off);
            v.y += __shfl_down(v.y, off);
            v.z += __shfl_down(v.z, off);
            v.w += __shfl_down(v.w, off);
        }
        if ((tid & 63) == 0) warr[tid >> 6] = v;
    }
    __syncthreads();
    if (tid < OUT_DIM) {
        float4 a = warr[2 * tid], b = warr[2 * tid + 1];
        vals[0][tid] = (a.x + b.x) * INV_TAU;
        vals[1][tid] = (a.y + b.y) * INV_TAU;
        vals[2][tid] = (a.z + b.z) * INV_TAU;
        vals[3][tid] = (a.w + b.w) * INV_TAU;
    }
    __syncthreads();
    if (tid < TB * OUT_DIM) {
        int t  = tid >> 3;
        int oo = tid & 7;
        float q = scaler_b[oo];
#pragma unroll
        for (int o2 = 0; o2 < OUT_DIM; ++o2)
            q = fmaf(vals[t][o2], scaler_w[oo * OUT_DIM + o2], q);
        out[(size_t)(b0 + t) * OUT_DIM + oo] = q;
    }
}

extern "C" void kernel_launch(void* const* d_in, const int* in_sizes, int n_in,
                              void* d_out, int out_size, void* d_ws, size_t ws_size,
                              hipStream_t stream)
{
    const float* x        = (const float*)d_in[0];
    const float* logic_w  = (const float*)d_in[1];
    const float* scaler_w = (const float*)d_in[2];
    const float* scaler_b = (const float*)d_in[3];
    const int*   idx0_a   = (const int*)d_in[4];
    const int*   idx0_b   = (const int*)d_in[5];
    const int*   idx_a    = (const int*)d_in[6];
    const int*   idx_b    = (const int*)d_in[7];
    float* out = (float*)d_out;

    const int n = N_LAYERS * HIDDEN;                 // 49152
    uint2*        coefp = (uint2*)d_ws;              // 384 KB
    unsigned int* idxp  = (unsigned int*)((char*)d_ws + (size_t)n * sizeof(uint2)); // 192 KB

    prep_kernel<<<(n + 255) / 256, 256, 0, stream>>>(logic_w, idx0_a, idx0_b,
                                                     idx_a, idx_b, coefp, idxp, n);
    net_kernel<<<BATCH / TB, NTH, 0, stream>>>(x, coefp, idxp,
                                               scaler_w, scaler_b, out);
}

// Round 7
// 117.535 us; speedup vs baseline: 1.1194x; 1.1194x over previous
//
#include <hip/hip_runtime.h>
#include <hip/hip_fp16.h>

// Problem constants (from reference)
constexpr int BATCH    = 4096;
constexpr int IN_DIM   = 1024;
constexpr int HIDDEN   = 8192;
constexpr int N_LAYERS = 6;
constexpr int OUT_DIM  = 8;
constexpr float INV_TAU = 0.1f;

// Tiling
constexpr int TB   = 8;             // batch rows per workgroup (8 fp16 = uint4)
constexpr int NTH  = 1024;          // threads per block (16 waves)
constexpr int NPT  = HIDDEN / NTH;  // neurons per thread = 8 (strided by 1024)
constexpr int NWAVES = NTH / 64;    // 16

__device__ __forceinline__ __half2 u2h(unsigned int u) {
    union { unsigned int u; __half2 h; } v; v.u = u; return v.h;
}
__device__ __forceinline__ unsigned int h2u(__half2 h) {
    union { unsigned int u; __half2 h; } v; v.h = h; return v.u;
}

// pack 4 fp32 -> 4 fp16 in a uint2 (prep kernel)
__device__ __forceinline__ uint2 pack4(float4 v) {
    __half2 lo = __float22half2_rn(make_float2(v.x, v.y));
    __half2 hi = __float22half2_rn(make_float2(v.z, v.w));
    uint2 r; r.x = h2u(lo); r.y = h2u(hi); return r;
}

// ---------------------------------------------------------------------------
// Kernel 1: packed per-neuron records:
//   coefp[l*H+j] = 4 fp16 gate coefs (c0,c1 | c2,c3)
//   idxp [l*H+j] = ia | (ib << 16)
// ---------------------------------------------------------------------------
__global__ void prep_kernel(const float* __restrict__ logic_w,
                            const int* __restrict__ idx0_a,
                            const int* __restrict__ idx0_b,
                            const int* __restrict__ idx_a,
                            const int* __restrict__ idx_b,
                            uint2* __restrict__ coefp,
                            unsigned int* __restrict__ idxp, int n)
{
    int id = blockIdx.x * blockDim.x + threadIdx.x;
    if (id >= n) return;
    const int l = id / HIDDEN;
    const int j = id - l * HIDDEN;

    int ia, ib;
    if (l == 0) { ia = idx0_a[j]; ib = idx0_b[j]; }
    else        { ia = idx_a[(size_t)(l - 1) * HIDDEN + j];
                  ib = idx_b[(size_t)(l - 1) * HIDDEN + j]; }
    idxp[id] = (unsigned int)ia | ((unsigned int)ib << 16);

    const float4* w4 = (const float4*)(logic_w + (size_t)id * 16);
    float4 wa = w4[0], wb = w4[1], wc = w4[2], wd = w4[3];
    float wv[16] = {wa.x, wa.y, wa.z, wa.w, wb.x, wb.y, wb.z, wb.w,
                    wc.x, wc.y, wc.z, wc.w, wd.x, wd.y, wd.z, wd.w};
    float m = wv[0];
#pragma unroll
    for (int i = 1; i < 16; ++i) m = fmaxf(m, wv[i]);
    float e[16];
    float s = 0.f;
#pragma unroll
    for (int i = 0; i < 16; ++i) { e[i] = expf(wv[i] - m); s += e[i]; }
    float inv = 1.f / s;
    const float G0[16] = {0,0,0,0,0,0,0,0, 1,1,1,1,1,1,1,1};
    const float G1[16] = {0,0,1,1,0,0,1,1, -1,-1,0,0,-1,-1,0,0};
    const float G2[16] = {0,0,0,0,1,1,1,1, -1,-1,-1,-1,0,0,0,0};
    const float G3[16] = {0,1,-1,0,-1,0,-2,-1, 1,2,0,1,0,1,-1,0};
    float c0 = 0.f, c1 = 0.f, c2 = 0.f, c3 = 0.f;
#pragma unroll
    for (int i = 0; i < 16; ++i) {
        float p = e[i] * inv;
        c0 = fmaf(p, G0[i], c0);
        c1 = fmaf(p, G1[i], c1);
        c2 = fmaf(p, G2[i], c2);
        c3 = fmaf(p, G3[i], c3);
    }
    coefp[id] = pack4(make_float4(c0, c1, c2, c3));
}

// gate in packed fp16 over 8 batch rows (uint4 = 4x half2):
// r = (c0 + c1*a) + b*(c2 + c3*a)
__device__ __forceinline__ uint4 gate8(uint4 a, uint4 b, uint2 c) {
    __half2 cp01 = u2h(c.x), cp23 = u2h(c.y);
    __half2 c0 = __low2half2(cp01), c1 = __high2half2(cp01);
    __half2 c2 = __low2half2(cp23), c3 = __high2half2(cp23);
    uint4 r;
    {
        __half2 av = u2h(a.x), bv = u2h(b.x);
        r.x = h2u(__hfma2(bv, __hfma2(c3, av, c2), __hfma2(c1, av, c0)));
    }
    {
        __half2 av = u2h(a.y), bv = u2h(b.y);
        r.y = h2u(__hfma2(bv, __hfma2(c3, av, c2), __hfma2(c1, av, c0)));
    }
    {
        __half2 av = u2h(a.z), bv = u2h(b.z);
        r.z = h2u(__hfma2(bv, __hfma2(c3, av, c2), __hfma2(c1, av, c0)));
    }
    {
        __half2 av = u2h(a.w), bv = u2h(b.w);
        r.w = h2u(__hfma2(bv, __hfma2(c3, av, c2), __hfma2(c1, av, c0)));
    }
    return r;
}

// ---------------------------------------------------------------------------
// Kernel 2: fused network, TB=8 rows/block. h = uint4[8192] = 128 KB (+16 KB
// hx) -> 1 block/CU, 512 blocks = 2 sequential rounds/CU (vs 4 at TB=4):
// per-row fixed costs (gather issue, tables, addressing) halve. Gathers are
// ds_read_b128 (R6 lesson: conflict cost ~ per instruction, wider is better);
// writes at 16 B lane stride cover banks uniformly (free). With 1 block/CU,
// VGPRs are free up to 128: next layer's idx+coef prefetched into registers
// so the post-barrier critical path starts directly with LDS gathers.
// ---------------------------------------------------------------------------
__global__ __launch_bounds__(NTH) void net_kernel(
    const float*  __restrict__ x,
    const uint2*  __restrict__ coefp,
    const unsigned int* __restrict__ idxp,
    const float*  __restrict__ scaler_w, const float* __restrict__ scaler_b,
    float* __restrict__ out)
{
    __shared__ uint4 h[HIDDEN];             // 128 KB: 8 fp16 rows / neuron
    __shared__ uint4 hx[IN_DIM];            // 16 KB
    __shared__ float warr[NWAVES][TB];      // 512 B: per-wave half-group sums
    __shared__ float vals[TB][OUT_DIM];     // 256 B

    const int tid = threadIdx.x;
    const int b0  = blockIdx.x * TB;

    // Load + binarize input tile (NTH == IN_DIM: one column per thread)
    {
        float v[TB];
#pragma unroll
        for (int r = 0; r < TB; ++r)
            v[r] = (x[(size_t)(b0 + r) * IN_DIM + tid] > 0.5f) ? 1.f : 0.f;
        uint4 p;
        p.x = h2u(__floats2half2_rn(v[0], v[1]));
        p.y = h2u(__floats2half2_rn(v[2], v[3]));
        p.z = h2u(__floats2half2_rn(v[4], v[5]));
        p.w = h2u(__floats2half2_rn(v[6], v[7]));
        hx[tid] = p;
    }

    uint4 acc[NPT];                 // 32 VGPRs
    unsigned int ij[NPT], ijn[NPT]; // 16 VGPRs
    uint2 cf[NPT], cfn[NPT];        // 32 VGPRs

    // Layer 0 tables up-front (overlaps x loads / hx writes)
#pragma unroll
    for (int k = 0; k < NPT; ++k) { ij[k] = idxp[k * NTH + tid]; cf[k] = coefp[k * NTH + tid]; }

    __syncthreads();                // hx visible

    // Layer 0: prefetch layer-1 tables, gather from hx
#pragma unroll
    for (int k = 0; k < NPT; ++k) {
        ijn[k] = idxp[HIDDEN + k * NTH + tid];
        cfn[k] = coefp[HIDDEN + k * NTH + tid];
    }
#pragma unroll
    for (int k = 0; k < NPT; ++k) {
        unsigned int pr = ij[k];
        acc[k] = gate8(hx[pr & 0xffffu], hx[pr >> 16], cf[k]);
    }
    // hx -> h disjoint: no barrier needed before writes
#pragma unroll
    for (int k = 0; k < NPT; ++k) h[k * NTH + tid] = acc[k];
    __syncthreads();

    // Layers 1..5: in-place on h (reads land in regs before writes)
    for (int l = 1; l < N_LAYERS; ++l) {
#pragma unroll
        for (int k = 0; k < NPT; ++k) { ij[k] = ijn[k]; cf[k] = cfn[k]; }
        if (l < N_LAYERS - 1) {
#pragma unroll
            for (int k = 0; k < NPT; ++k) {
                ijn[k] = idxp[(size_t)(l + 1) * HIDDEN + k * NTH + tid];
                cfn[k] = coefp[(size_t)(l + 1) * HIDDEN + k * NTH + tid];
            }
        }
#pragma unroll
        for (int k = 0; k < NPT; ++k) {
            unsigned int pr = ij[k];
            acc[k] = gate8(h[pr & 0xffffu], h[pr >> 16], cf[k]);
        }
        __syncthreads();            // all reads of h done
#pragma unroll
        for (int k = 0; k < NPT; ++k) h[k * NTH + tid] = acc[k];
        __syncthreads();
    }

    // Epilogue: group k = tid>>7; sum 8 neurons at stride 128 (uniform banks),
    // fp32 accumulation over 8 rows; 64-lane butterfly; wave wv = half of
    // group wv>>1.
    {
        const int k    = tid >> 7;
        const int base = k * 1024 + (tid & 127);
        float s[TB] = {0.f, 0.f, 0.f, 0.f, 0.f, 0.f, 0.f, 0.f};
#pragma unroll
        for (int i = 0; i < 8; ++i) {
            uint4 t = h[base + 128 * i];
            float2 f0 = __half22float2(u2h(t.x));
            float2 f1 = __half22float2(u2h(t.y));
            float2 f2 = __half22float2(u2h(t.z));
            float2 f3 = __half22float2(u2h(t.w));
            s[0] += f0.x; s[1] += f0.y; s[2] += f1.x; s[3] += f1.y;
            s[4] += f2.x; s[5] += f2.y; s[6] += f3.x; s[7] += f3.y;
        }
#pragma unroll
        for (int off = 32; off > 0; off >>= 1) {
#pragma unroll
            for (int r = 0; r < TB; ++r) s[r] += __shfl_down(s[r], off);
        }
        if ((tid & 63) == 0) {
#pragma unroll
            for (int r = 0; r < TB; ++r) warr[tid >> 6][r] = s[r];
        }
    }
    __syncthreads();
    if (tid < TB * OUT_DIM) {       // 64 threads: values, then scaler GEMV
        int r = tid >> 3;
        int k = tid & 7;
        vals[r][k] = (warr[2 * k][r] + warr[2 * k + 1][r]) * INV_TAU;
    }
    __syncthreads();
    if (tid < TB * OUT_DIM) {
        int r = tid >> 3;
        int o = tid & 7;
        float q = scaler_b[o];
#pragma unroll
        for (int k = 0; k < OUT_DIM; ++k)
            q = fmaf(vals[r][k], scaler_w[o * OUT_DIM + k], q);
        out[(size_t)(b0 + r) * OUT_DIM + o] = q;
    }
}

extern "C" void kernel_launch(void* const* d_in, const int* in_sizes, int n_in,
                              void* d_out, int out_size, void* d_ws, size_t ws_size,
                              hipStream_t stream)
{
    const float* x        = (const float*)d_in[0];
    const float* logic_w  = (const float*)d_in[1];
    const float* scaler_w = (const float*)d_in[2];
    const float* scaler_b = (const float*)d_in[3];
    const int*   idx0_a   = (const int*)d_in[4];
    const int*   idx0_b   = (const int*)d_in[5];
    const int*   idx_a    = (const int*)d_in[6];
    const int*   idx_b    = (const int*)d_in[7];
    float* out = (float*)d_out;

    const int n = N_LAYERS * HIDDEN;                 // 49152
    uint2*        coefp = (uint2*)d_ws;              // 384 KB
    unsigned int* idxp  = (unsigned int*)((char*)d_ws + (size_t)n * sizeof(uint2)); // 192 KB

    prep_kernel<<<(n + 255) / 256, 256, 0, stream>>>(logic_w, idx0_a, idx0_b,
                                                     idx_a, idx_b, coefp, idxp, n);
    net_kernel<<<BATCH / TB, NTH, 0, stream>>>(x, coefp, idxp,
                                               scaler_w, scaler_b, out);
}